// Round 15
// baseline (368.038 us; speedup 1.0000x reference)
//
#include <hip/hip_runtime.h>
#include <hip/hip_bf16.h>
#include <cstdint>

typedef __bf16 bf16;
typedef bf16 bf16x4 __attribute__((ext_vector_type(4)));
typedef bf16 bf16x8 __attribute__((ext_vector_type(8)));
typedef float f32x4 __attribute__((ext_vector_type(4)));

#define B_  2048
#define E_  512
#define H_  512
#define V_  50257
#define K1_ 1024
#define VPAD_ 50432   // 197*256

// Wo conversion split (float4 units)
#define CONV_TOT  6432896   // V_*512/4
#define CONV_PAD  6455296   // VPAD_*512/4
#define CONV_HALF 3216448

#define BAR() __builtin_amdgcn_s_barrier()
#define WAIT_LGKM0() do { asm volatile("s_waitcnt lgkmcnt(0)" ::: "memory"); \
                          __builtin_amdgcn_sched_barrier(0); } while (0)

__device__ __forceinline__ void gload_lds16(const void* g, void* l) {
  __builtin_amdgcn_global_load_lds(
      (const __attribute__((address_space(1))) void*)g,
      (__attribute__((address_space(3))) void*)l, 16, 0, 0);
}

__device__ __forceinline__ float wave_sum(float v) {
#pragma unroll
  for (int o = 32; o > 0; o >>= 1) v += __shfl_xor(v, o, 64);
  return v;
}

__device__ __forceinline__ void cvt_store4(const float* __restrict__ src,
                                           bf16* __restrict__ dst, size_t e) {
  f32x4 v = *reinterpret_cast<const f32x4*>(src + e);
  bf16x4 t; t[0]=(bf16)v[0]; t[1]=(bf16)v[1]; t[2]=(bf16)v[2]; t[3]=(bf16)v[3];
  *reinterpret_cast<bf16x4*>(dst + e) = t;
}

// ---------------------------------------------------------------------------
// prep_small: gru_in bf16 [2048][1024]; wzrh bf16 [1536][1024]  (~7.5 MB)
// ---------------------------------------------------------------------------
__global__ __launch_bounds__(256) void prep_kernel(
    const float* __restrict__ hprev, const float* __restrict__ x,
    const float* __restrict__ Wz, const float* __restrict__ Wr,
    const float* __restrict__ Wh,
    bf16* __restrict__ gin, bf16* __restrict__ wzrh)
{
  const int i = blockIdx.x * 256 + threadIdx.x;
  constexpr int N1 = B_ * K1_ / 4;
  constexpr int N2 = 1536 * K1_ / 4;
  if (i < N1) {
    int e = i * 4;
    int m = e >> 10, k = e & 1023;
    const float* src = (k < 512) ? (hprev + (size_t)m * 512 + k)
                                 : (x + (size_t)m * 512 + (k - 512));
    f32x4 v = *reinterpret_cast<const f32x4*>(src);
    bf16x4 t; t[0]=(bf16)v[0]; t[1]=(bf16)v[1]; t[2]=(bf16)v[2]; t[3]=(bf16)v[3];
    *reinterpret_cast<bf16x4*>(gin + e) = t;
  } else if (i < N1 + N2) {
    int e = (i - N1) * 4;
    int which = e >> 19;
    int off = e & ((1 << 19) - 1);
    const float* W = (which == 0) ? Wz : (which == 1) ? Wr : Wh;
    f32x4 v = *reinterpret_cast<const f32x4*>(W + off);
    bf16x4 t; t[0]=(bf16)v[0]; t[1]=(bf16)v[1]; t[2]=(bf16)v[2]; t[3]=(bf16)v[3];
    *reinterpret_cast<bf16x4*>(wzrh + e) = t;
  }
}

// ---------------------------------------------------------------------------
// gemm64_zr: BM=64, BN=128, BK=64 GEMM for z/r pre-acts (M=2048,N=1024,K=1024)
// blocks [256, 2304) convert the FIRST half of Wo fp32 -> wob bf16.
// ---------------------------------------------------------------------------
__global__ __launch_bounds__(256) void gemm64_zr(
    const bf16* __restrict__ A, const bf16* __restrict__ Bm,
    float* __restrict__ C,
    const float* __restrict__ Wo, bf16* __restrict__ wob)
{
  const int bx = blockIdx.x;
  const int tid = threadIdx.x;
  if (bx >= 256) {               // Wo conversion, first half
    const size_t cb = bx - 256;
    for (size_t idx = cb * 256 + tid; idx < CONV_HALF; idx += (size_t)2048 * 256)
      cvt_store4(Wo, wob, idx * 4);
    return;
  }
  constexpr int N = 1024, K = K1_;
  __shared__ bf16 As[2][64 * 64];
  __shared__ bf16 Bs[2][128 * 64];
  const int wid = tid >> 6, lane = tid & 63;
  const int bm = bx & 31, bn = bx >> 5;
  const int wm = (wid >> 1) * 32, wn = (wid & 1) * 64;
  f32x4 acc[2][4] = {};
  const size_t a_row0 = (size_t)bm * 64;
  const size_t b_row0 = (size_t)bn * 128;

  auto STAGE = [&](int buf, int k0) {
#pragma unroll
    for (int i = 0; i < 2; ++i) {
      int base = i * 256 + wid * 64;
      int idx = base + lane;
      int row = idx >> 3;
      int col = ((idx & 7) ^ (row & 7)) << 3;
      gload_lds16(A + (a_row0 + row) * K + (k0 + col), &As[buf][base * 8]);
    }
#pragma unroll
    for (int i = 0; i < 4; ++i) {
      int base = i * 256 + wid * 64;
      int idx = base + lane;
      int row = idx >> 3;
      int col = ((idx & 7) ^ (row & 7)) << 3;
      gload_lds16(Bm + (b_row0 + row) * K + (k0 + col), &Bs[buf][base * 8]);
    }
  };

  auto COMPUTE = [&](int buf) {
#pragma unroll
    for (int kk = 0; kk < 2; ++kk) {
      bf16x8 af[2], bb[4];
#pragma unroll
      for (int i = 0; i < 2; ++i) {
        int ra = wm + i * 16 + (lane & 15);
        int ca = (kk * 32 + (lane >> 4) * 8) ^ ((ra & 7) << 3);
        af[i] = *reinterpret_cast<const bf16x8*>(&As[buf][ra * 64 + ca]);
      }
#pragma unroll
      for (int j = 0; j < 4; ++j) {
        int rb = wn + j * 16 + (lane & 15);
        int cb2 = (kk * 32 + (lane >> 4) * 8) ^ ((rb & 7) << 3);
        bb[j] = *reinterpret_cast<const bf16x8*>(&Bs[buf][rb * 64 + cb2]);
      }
      __builtin_amdgcn_s_setprio(1);
#pragma unroll
      for (int i = 0; i < 2; ++i)
#pragma unroll
        for (int j = 0; j < 4; ++j)
          acc[i][j] = __builtin_amdgcn_mfma_f32_16x16x32_bf16(af[i], bb[j], acc[i][j], 0, 0, 0);
      __builtin_amdgcn_s_setprio(0);
    }
  };

  STAGE(0, 0);
  asm volatile("s_waitcnt vmcnt(0)" ::: "memory");
  __syncthreads();
  const int nt = K >> 6;
  int cur = 0;
  for (int t = 0; t < nt - 1; ++t) {
    STAGE(cur ^ 1, (t + 1) << 6);
    COMPUTE(cur);
    asm volatile("s_waitcnt vmcnt(0)" ::: "memory");
    __syncthreads();
    cur ^= 1;
  }
  COMPUTE(cur);

  const int r0 = (lane >> 4) * 4, cc = lane & 15;
#pragma unroll
  for (int i = 0; i < 2; ++i)
#pragma unroll
    for (int j = 0; j < 4; ++j) {
      int n = bn * 128 + wn + j * 16 + cc;
#pragma unroll
      for (int q = 0; q < 4; ++q) {
        int mm = bm * 64 + wm + i * 16 + r0 + q;
        C[(size_t)mm * N + n] = acc[i][j][q];
      }
    }
}

// ---------------------------------------------------------------------------
// gemm64 (generic, for h pre-act): BM=64, BN=128, BK=64
// ---------------------------------------------------------------------------
__global__ __launch_bounds__(256) void gemm64(
    const bf16* __restrict__ A, const bf16* __restrict__ Bm,
    float* __restrict__ C, int M, int N, int K)
{
  __shared__ bf16 As[2][64 * 64];
  __shared__ bf16 Bs[2][128 * 64];
  const int tid = threadIdx.x;
  const int wid = tid >> 6, lane = tid & 63;
  const int bm = blockIdx.x, bn = blockIdx.y;
  const int wm = (wid >> 1) * 32, wn = (wid & 1) * 64;
  f32x4 acc[2][4] = {};
  const size_t a_row0 = (size_t)bm * 64;
  const size_t b_row0 = (size_t)bn * 128;

  auto STAGE = [&](int buf, int k0) {
#pragma unroll
    for (int i = 0; i < 2; ++i) {
      int base = i * 256 + wid * 64;
      int idx = base + lane;
      int row = idx >> 3;
      int col = ((idx & 7) ^ (row & 7)) << 3;
      gload_lds16(A + (a_row0 + row) * K + (k0 + col), &As[buf][base * 8]);
    }
#pragma unroll
    for (int i = 0; i < 4; ++i) {
      int base = i * 256 + wid * 64;
      int idx = base + lane;
      int row = idx >> 3;
      int col = ((idx & 7) ^ (row & 7)) << 3;
      gload_lds16(Bm + (b_row0 + row) * K + (k0 + col), &Bs[buf][base * 8]);
    }
  };

  auto COMPUTE = [&](int buf) {
#pragma unroll
    for (int kk = 0; kk < 2; ++kk) {
      bf16x8 af[2], bb[4];
#pragma unroll
      for (int i = 0; i < 2; ++i) {
        int ra = wm + i * 16 + (lane & 15);
        int ca = (kk * 32 + (lane >> 4) * 8) ^ ((ra & 7) << 3);
        af[i] = *reinterpret_cast<const bf16x8*>(&As[buf][ra * 64 + ca]);
      }
#pragma unroll
      for (int j = 0; j < 4; ++j) {
        int rb = wn + j * 16 + (lane & 15);
        int cb = (kk * 32 + (lane >> 4) * 8) ^ ((rb & 7) << 3);
        bb[j] = *reinterpret_cast<const bf16x8*>(&Bs[buf][rb * 64 + cb]);
      }
      __builtin_amdgcn_s_setprio(1);
#pragma unroll
      for (int i = 0; i < 2; ++i)
#pragma unroll
        for (int j = 0; j < 4; ++j)
          acc[i][j] = __builtin_amdgcn_mfma_f32_16x16x32_bf16(af[i], bb[j], acc[i][j], 0, 0, 0);
      __builtin_amdgcn_s_setprio(0);
    }
  };

  STAGE(0, 0);
  asm volatile("s_waitcnt vmcnt(0)" ::: "memory");
  __syncthreads();
  const int nt = K >> 6;
  int cur = 0;
  for (int t = 0; t < nt - 1; ++t) {
    STAGE(cur ^ 1, (t + 1) << 6);
    COMPUTE(cur);
    asm volatile("s_waitcnt vmcnt(0)" ::: "memory");
    __syncthreads();
    cur ^= 1;
  }
  COMPUTE(cur);

  const int r0 = (lane >> 4) * 4, cc = lane & 15;
#pragma unroll
  for (int i = 0; i < 2; ++i)
#pragma unroll
    for (int j = 0; j < 4; ++j) {
      int n = bn * 128 + wn + j * 16 + cc;
#pragma unroll
      for (int q = 0; q < 4; ++q) {
        int mm = bm * 64 + wm + i * 16 + r0 + q;
        C[(size_t)mm * N + n] = acc[i][j][q];
      }
    }
}

// ---------------------------------------------------------------------------
// LN(+bias) + sigmoid for z and r; blocks [2048,4096) convert Wo 2nd half+pad
// ---------------------------------------------------------------------------
__global__ __launch_bounds__(256) void ln_zr_kernel(
    const float* __restrict__ zrp,
    const float* __restrict__ bz, const float* __restrict__ br,
    const float* __restrict__ gz, const float* __restrict__ bez,
    const float* __restrict__ gr, const float* __restrict__ ber,
    const float* __restrict__ hprev, const float* __restrict__ x,
    float* __restrict__ zbuf, bf16* __restrict__ cand,
    const float* __restrict__ Wo, bf16* __restrict__ wob)
{
  const int bx = blockIdx.x, tid = threadIdx.x;
  if (bx >= 2048) {
    const size_t cb = bx - 2048;
    for (size_t idx = CONV_HALF + cb * 256 + tid; idx < CONV_PAD;
         idx += (size_t)2048 * 256) {
      if (idx < CONV_TOT) {
        cvt_store4(Wo, wob, idx * 4);
      } else {
        bf16x4 t = {};
        *reinterpret_cast<bf16x4*>(wob + idx * 4) = t;
      }
    }
    return;
  }
  const int m = bx;
  const int wid = tid >> 6, lane = tid & 63;
  float zv[2], rv[2];
  float s0 = 0, s1 = 0, s2 = 0, s3 = 0;
#pragma unroll
  for (int e = 0; e < 2; ++e) {
    int n = tid + e * 256;
    float a = zrp[(size_t)m * 1024 + n] + bz[n];
    float b = zrp[(size_t)m * 1024 + 512 + n] + br[n];
    zv[e] = a; rv[e] = b;
    s0 += a; s1 += a * a; s2 += b; s3 += b * b;
  }
  s0 = wave_sum(s0); s1 = wave_sum(s1); s2 = wave_sum(s2); s3 = wave_sum(s3);
  __shared__ float red[4][4];
  if (lane == 0) { red[wid][0] = s0; red[wid][1] = s1; red[wid][2] = s2; red[wid][3] = s3; }
  __syncthreads();
  float zs = red[0][0] + red[1][0] + red[2][0] + red[3][0];
  float zq = red[0][1] + red[1][1] + red[2][1] + red[3][1];
  float rs = red[0][2] + red[1][2] + red[2][2] + red[3][2];
  float rq = red[0][3] + red[1][3] + red[2][3] + red[3][3];
  float zm = zs * (1.f / 512.f), zvr = zq * (1.f / 512.f) - zm * zm;
  float rm = rs * (1.f / 512.f), rvr = rq * (1.f / 512.f) - rm * rm;
  float zrs_ = rsqrtf(zvr + 1e-5f), rrs = rsqrtf(rvr + 1e-5f);
#pragma unroll
  for (int e = 0; e < 2; ++e) {
    int n = tid + e * 256;
    float zval = 1.f / (1.f + expf(-((zv[e] - zm) * zrs_ * gz[n] + bez[n])));
    float rval = 1.f / (1.f + expf(-((rv[e] - rm) * rrs * gr[n] + ber[n])));
    zbuf[(size_t)m * 512 + n] = zval;
    cand[(size_t)m * 1024 + n] = (bf16)(hprev[(size_t)m * 512 + n] * rval);
    cand[(size_t)m * 1024 + 512 + n] = (bf16)(x[(size_t)m * 512 + n]);
  }
}

// ---------------------------------------------------------------------------
// LN(+bias) + tanh for h_new; h_t = (1-z)*h_prev + z*h_new
// ---------------------------------------------------------------------------
__global__ __launch_bounds__(256) void ln_h_kernel(
    const float* __restrict__ hpre, const float* __restrict__ bh,
    const float* __restrict__ gh, const float* __restrict__ beh,
    const float* __restrict__ zbuf, const float* __restrict__ hprev,
    float* __restrict__ outh, bf16* __restrict__ htb)
{
  const int m = blockIdx.x, tid = threadIdx.x;
  const int wid = tid >> 6, lane = tid & 63;
  float v[2];
  float s0 = 0, s1 = 0;
#pragma unroll
  for (int e = 0; e < 2; ++e) {
    int n = tid + e * 256;
    float a = hpre[(size_t)m * 512 + n] + bh[n];
    v[e] = a; s0 += a; s1 += a * a;
  }
  s0 = wave_sum(s0); s1 = wave_sum(s1);
  __shared__ float red[4][2];
  if (lane == 0) { red[wid][0] = s0; red[wid][1] = s1; }
  __syncthreads();
  float ss = red[0][0] + red[1][0] + red[2][0] + red[3][0];
  float sq = red[0][1] + red[1][1] + red[2][1] + red[3][1];
  float mean = ss * (1.f / 512.f), var = sq * (1.f / 512.f) - mean * mean;
  float rstd = rsqrtf(var + 1e-5f);
#pragma unroll
  for (int e = 0; e < 2; ++e) {
    int n = tid + e * 256;
    float hn = tanhf((v[e] - mean) * rstd * gh[n] + beh[n]);
    float z = zbuf[(size_t)m * 512 + n];
    float ht = (1.f - z) * hprev[(size_t)m * 512 + n] + z * hn;
    outh[(size_t)m * 512 + n] = ht;
    htb[(size_t)m * 512 + n] = (bf16)ht;
  }
}

// ---------------------------------------------------------------------------
// big GEMM v10: 8-phase template with PEELED last iteration.
// Iterations 0..2: identical to r13 (stages + 16 barriers/iter, vmcnt(4)).
// Iteration 3: ph1-ph4 keep barriers (stage + consume B(k=7)); after ph4's
// vmcnt(0)+barrier NO LDS writes remain -> ph5-ph8 run barrier-free, and
// each output quadrant is stored immediately after its final MFMA (stores
// drain under remaining MFMAs; waves free-run to endpgm).
// ---------------------------------------------------------------------------
__global__ __launch_bounds__(512, 2) void gemm_out256(
    const bf16* __restrict__ A, const bf16* __restrict__ Wb,
    const float* __restrict__ bo, float* __restrict__ Y)
{
  __shared__ bf16 lds[2][2][2][128 * 64];
  const int tid = threadIdx.x;
  const int lane = tid & 63;
  const int wid = tid >> 6;
  const int wr = wid >> 2, wc = wid & 3;
  const int hw = blockIdx.x;
  const int logical = (hw & 7) * 197 + (hw >> 3);
  const int bm = logical & 7;
  const int bn = logical >> 3;
  const size_t a_row0 = (size_t)bm * 256;
  const size_t b_row0 = (size_t)bn * 256;
  f32x4 acc[8][4] = {};

  auto STAGE = [&](int p, int op, int h, int ks) {
    const bf16* src = op ? Wb : A;
    const size_t r0 = (op ? b_row0 : a_row0) + h * 128;
    const int k0 = ks << 6;
#pragma unroll
    for (int l = 0; l < 2; ++l) {
      int idx = l * 512 + tid;
      int row = idx >> 3;
      int ch = ((idx & 7) ^ (row & 7)) << 3;
      gload_lds16(src + (r0 + row) * 512 + k0 + ch,
                  &lds[p][op][h][(l * 512 + (tid & ~63)) * 8]);
    }
  };

  auto rdA = [&](int p, int i, int kk) -> bf16x8 {
    int lr = i * 16 + (lane & 15);
    int ch = ((kk * 4 + (lane >> 4)) ^ (lr & 7)) << 3;
    return *reinterpret_cast<const bf16x8*>(&lds[p][0][wr][lr * 64 + ch]);
  };
  auto rdB = [&](int p, int j, int kk) -> bf16x8 {
    int gr = wc * 64 + j * 16 + (lane & 15);
    int lr = gr & 127;
    int ch = ((kk * 4 + (lane >> 4)) ^ (lr & 7)) << 3;
    return *reinterpret_cast<const bf16x8*>(&lds[p][1][wc >> 1][lr * 64 + ch]);
  };

  bf16x8 a0[4][2], a1[4][2], bb0[2][2], bb1[2][2];

  auto MM = [&](bf16x8 (&af)[4][2], bf16x8 (&bf)[2][2], int ib, int jb) {
    __builtin_amdgcn_s_setprio(1);
#pragma unroll
    for (int i = 0; i < 4; ++i)
#pragma unroll
      for (int j = 0; j < 2; ++j)
#pragma unroll
        for (int kk = 0; kk < 2; ++kk)
          acc[ib + i][jb + j] =
              __builtin_amdgcn_mfma_f32_16x16x32_bf16(af[i][kk], bf[j][kk],
                                                      acc[ib + i][jb + j], 0, 0, 0);
    __builtin_amdgcn_s_setprio(0);
  };

  STAGE(0, 0, 0, 0); STAGE(0, 0, 1, 0); STAGE(0, 1, 0, 0); STAGE(0, 1, 1, 0);
  STAGE(1, 0, 0, 1); STAGE(1, 0, 1, 1);
  asm volatile("s_waitcnt vmcnt(4)" ::: "memory");
  BAR();

  // ---- iterations 0..2 (all stages active) ----
#pragma unroll 1
  for (int it = 0; it < 3; ++it) {
    const int s = 2 * it;
    // ph1
#pragma unroll
    for (int i = 0; i < 4; ++i) { a0[i][0] = rdA(0, i, 0); a0[i][1] = rdA(0, i, 1); }
#pragma unroll
    for (int j = 0; j < 2; ++j) { bb0[j][0] = rdB(0, j, 0); bb0[j][1] = rdB(0, j, 1); }
    STAGE(1, 1, 0, s + 1);
    BAR(); WAIT_LGKM0();
    MM(a0, bb0, 0, 0);
    BAR();
    // ph2
#pragma unroll
    for (int i = 0; i < 4; ++i) { a1[i][0] = rdA(0, 4 + i, 0); a1[i][1] = rdA(0, 4 + i, 1); }
    STAGE(1, 1, 1, s + 1);
    BAR(); WAIT_LGKM0();
    MM(a1, bb0, 4, 0);
    BAR();
    // ph3
#pragma unroll
    for (int j = 0; j < 2; ++j) { bb1[j][0] = rdB(0, 2 + j, 0); bb1[j][1] = rdB(0, 2 + j, 1); }
    STAGE(0, 0, 0, s + 2);
    BAR(); WAIT_LGKM0();
    MM(a0, bb1, 0, 2);
    BAR();
    // ph4
    STAGE(0, 1, 0, s + 2);
    asm volatile("s_waitcnt vmcnt(4)" ::: "memory");
    BAR();
    MM(a1, bb1, 4, 2);
    BAR();
    // ph5
#pragma unroll
    for (int i = 0; i < 4; ++i) { a0[i][0] = rdA(1, i, 0); a0[i][1] = rdA(1, i, 1); }
#pragma unroll
    for (int j = 0; j < 2; ++j) { bb0[j][0] = rdB(1, j, 0); bb0[j][1] = rdB(1, j, 1); }
    STAGE(0, 0, 1, s + 2);
    BAR(); WAIT_LGKM0();
    MM(a0, bb0, 0, 0);
    BAR();
    // ph6
#pragma unroll
    for (int i = 0; i < 4; ++i) { a1[i][0] = rdA(1, 4 + i, 0); a1[i][1] = rdA(1, 4 + i, 1); }
    STAGE(0, 1, 1, s + 2);
    BAR(); WAIT_LGKM0();
    MM(a1, bb0, 4, 0);
    BAR();
    // ph7
#pragma unroll
    for (int j = 0; j < 2; ++j) { bb1[j][0] = rdB(1, 2 + j, 0); bb1[j][1] = rdB(1, 2 + j, 1); }
    STAGE(1, 0, 0, s + 3);
    BAR(); WAIT_LGKM0();
    MM(a0, bb1, 0, 2);
    BAR();
    // ph8
    STAGE(1, 0, 1, s + 3);
    asm volatile("s_waitcnt vmcnt(4)" ::: "memory");
    BAR();
    MM(a1, bb1, 4, 2);
    BAR();
  }

  // ---- peeled iteration 3 (k-steps 6,7) ----
  // bias/valid precompute (short live range, before free-run section)
  const int r0q = (lane >> 4) * 4, cc = lane & 15;
  const int rowbase = (int)a_row0 + wr * 128;
  const int colbase = (int)b_row0 + wc * 64;
  float bia[4]; bool val[4];
#pragma unroll
  for (int j = 0; j < 4; ++j) {
    int n = colbase + j * 16 + cc;
    val[j] = (n < V_);
    bia[j] = val[j] ? bo[n] : 0.f;
  }

  auto STORE_Q = [&](int ib, int jb) {   // one quadrant: 4 i x 4 q x 2 j
#pragma unroll
    for (int i = 0; i < 4; ++i) {
#pragma unroll
      for (int q = 0; q < 4; ++q) {
        size_t rowoff = (size_t)(rowbase + (ib + i) * 16 + r0q + q) * V_;
#pragma unroll
        for (int j = 0; j < 2; ++j) {
          if (val[jb + j])
            Y[rowoff + colbase + (jb + j) * 16 + cc] = acc[ib + i][jb + j][q] + bia[jb + j];
        }
      }
    }
  };

  // ph1 (k=6)
#pragma unroll
  for (int i = 0; i < 4; ++i) { a0[i][0] = rdA(0, i, 0); a0[i][1] = rdA(0, i, 1); }
#pragma unroll
  for (int j = 0; j < 2; ++j) { bb0[j][0] = rdB(0, j, 0); bb0[j][1] = rdB(0, j, 1); }
  STAGE(1, 1, 0, 7);
  BAR(); WAIT_LGKM0();
  MM(a0, bb0, 0, 0);
  BAR();
  // ph2
#pragma unroll
  for (int i = 0; i < 4; ++i) { a1[i][0] = rdA(0, 4 + i, 0); a1[i][1] = rdA(0, 4 + i, 1); }
  STAGE(1, 1, 1, 7);
  BAR(); WAIT_LGKM0();
  MM(a1, bb0, 4, 0);
  BAR();
  // ph3
#pragma unroll
  for (int j = 0; j < 2; ++j) { bb1[j][0] = rdB(0, 2 + j, 0); bb1[j][1] = rdB(0, 2 + j, 1); }
  BAR(); WAIT_LGKM0();
  MM(a0, bb1, 0, 2);
  BAR();
  // ph4: all B(7) loads must be in LDS for every wave
  asm volatile("s_waitcnt vmcnt(0)" ::: "memory");
  BAR();
  MM(a1, bb1, 4, 2);
  BAR();

  // ---- k=7: barrier-free, stores fused after each quadrant's final MFMA ----
#pragma unroll
  for (int i = 0; i < 4; ++i) { a0[i][0] = rdA(1, i, 0); a0[i][1] = rdA(1, i, 1); }
#pragma unroll
  for (int j = 0; j < 2; ++j) { bb0[j][0] = rdB(1, j, 0); bb0[j][1] = rdB(1, j, 1); }
  WAIT_LGKM0();
  MM(a0, bb0, 0, 0);
  STORE_Q(0, 0);
#pragma unroll
  for (int i = 0; i < 4; ++i) { a1[i][0] = rdA(1, 4 + i, 0); a1[i][1] = rdA(1, 4 + i, 1); }
  WAIT_LGKM0();
  MM(a1, bb0, 4, 0);
  STORE_Q(4, 0);
#pragma unroll
  for (int j = 0; j < 2; ++j) { bb1[j][0] = rdB(1, 2 + j, 0); bb1[j][1] = rdB(1, 2 + j, 1); }
  WAIT_LGKM0();
  MM(a0, bb1, 0, 2);
  STORE_Q(0, 2);
  MM(a1, bb1, 4, 2);
  STORE_Q(4, 2);
}

// ---------------------------------------------------------------------------
// fallback path (ws too small): fp32 Wo reg-staged GEMM
// ---------------------------------------------------------------------------
__global__ __launch_bounds__(256) void gemm_out_kernel(
    const bf16* __restrict__ A, const float* __restrict__ Wo,
    const float* __restrict__ bo, float* __restrict__ Y)
{
  __shared__ bf16 As[128 * 64];
  __shared__ bf16 Bs[128 * 64];
  constexpr int K = 512;
  const int tid = threadIdx.x;
  const int wid = tid >> 6, lane = tid & 63;
  const int bm = blockIdx.x, bn = blockIdx.y;
  const int wm = (wid >> 1) * 64, wn = (wid & 1) * 64;
  f32x4 acc[4][4] = {};

  for (int k0 = 0; k0 < K; k0 += 64) {
#pragma unroll
    for (int i = 0; i < 4; ++i) {
      int base = i * 256 + wid * 64;
      int idx = base + lane;
      int row = idx >> 3, col = (idx & 7) << 3;
      gload_lds16(A + ((size_t)bm * 128 + row) * K + (k0 + col), &As[base * 8]);
    }
#pragma unroll
    for (int i = 0; i < 8; ++i) {
      int idx = i * 256 + tid;
      int row = idx >> 4;
      int c4 = (idx & 15) * 4;
      int n = bn * 128 + row;
      int nc = (n < V_) ? n : (V_ - 1);
      f32x4 v = *reinterpret_cast<const f32x4*>(Wo + (size_t)nc * K + k0 + c4);
      bf16x4 t; t[0]=(bf16)v[0]; t[1]=(bf16)v[1]; t[2]=(bf16)v[2]; t[3]=(bf16)v[3];
      *reinterpret_cast<bf16x4*>(&Bs[row * 64 + c4]) = t;
    }
    asm volatile("s_waitcnt vmcnt(0)" ::: "memory");
    __syncthreads();
#pragma unroll
    for (int kk = 0; kk < 2; ++kk) {
      bf16x8 af[4], bb[4];
#pragma unroll
      for (int i = 0; i < 4; ++i)
        af[i] = *reinterpret_cast<const bf16x8*>(
            &As[(wm + i * 16 + (lane & 15)) * 64 + kk * 32 + (lane >> 4) * 8]);
#pragma unroll
      for (int j = 0; j < 4; ++j)
        bb[j] = *reinterpret_cast<const bf16x8*>(
            &Bs[(wn + j * 16 + (lane & 15)) * 64 + kk * 32 + (lane >> 4) * 8]);
#pragma unroll
      for (int i = 0; i < 4; ++i)
#pragma unroll
        for (int j = 0; j < 4; ++j)
          acc[i][j] = __builtin_amdgcn_mfma_f32_16x16x32_bf16(af[i], bb[j], acc[i][j], 0, 0, 0);
    }
    __syncthreads();
  }

  const int r0 = (lane >> 4) * 4, cc = lane & 15;
#pragma unroll
  for (int i = 0; i < 4; ++i)
#pragma unroll
    for (int j = 0; j < 4; ++j) {
      int n = bn * 128 + wn + j * 16 + cc;
      if (n < V_) {
        float bia = bo[n];
#pragma unroll
        for (int q = 0; q < 4; ++q) {
          int mm = bm * 128 + wm + i * 16 + r0 + q;
          Y[(size_t)mm * V_ + n] = acc[i][j][q] + bia;
        }
      }
    }
}

// ---------------------------------------------------------------------------
extern "C" void kernel_launch(void* const* d_in, const int* in_sizes, int n_in,
                              void* d_out, int out_size, void* d_ws, size_t ws_size,
                              hipStream_t stream) {
  const float* x     = (const float*)d_in[0];
  const float* hprev = (const float*)d_in[1];
  const float* Wz    = (const float*)d_in[2];
  const float* bz    = (const float*)d_in[3];
  const float* gz    = (const float*)d_in[4];
  const float* bez   = (const float*)d_in[5];
  const float* Wr    = (const float*)d_in[6];
  const float* br    = (const float*)d_in[7];
  const float* gr    = (const float*)d_in[8];
  const float* ber   = (const float*)d_in[9];
  const float* Wh    = (const float*)d_in[10];
  const float* bh    = (const float*)d_in[11];
  const float* gh    = (const float*)d_in[12];
  const float* beh   = (const float*)d_in[13];
  const float* Wo    = (const float*)d_in[14];
  const float* bo    = (const float*)d_in[15];

  float* out_h = (float*)d_out;
  float* out_y = out_h + (size_t)B_ * H_;

  char* ws = (char*)d_ws;
  bf16*  gin  = (bf16*)(ws);                      // 4 MB   [2048][1024]
  bf16*  wzrh = (bf16*)(ws + ((size_t)4 << 20));  // 3 MB   [1536][1024]
  float* zrp  = (float*)(ws + ((size_t)7 << 20)); // 8 MB   [2048][1024]
  float* zbuf = (float*)(ws + ((size_t)15 << 20));// 4 MB   [2048][512]
  bf16*  cand = (bf16*)(ws + ((size_t)19 << 20)); // 4 MB   [2048][1024]
  float* hpre = (float*)(ws + ((size_t)23 << 20));// 4 MB   [2048][512]
  bf16*  htb  = (bf16*)(ws + ((size_t)27 << 20)); // 2 MB   [2048][512]
  bf16*  wob  = (bf16*)(ws + ((size_t)29 << 20)); // 51.6 MB [VPAD_][512]

  constexpr size_t NEED = ((size_t)29 << 20) + (size_t)VPAD_ * 512 * 2;
  const bool big = (ws_size >= NEED);

  prep_kernel<<<3584, 256, 0, stream>>>(hprev, x, Wz, Wr, Wh, gin, wzrh);
  gemm64_zr<<<big ? 2304 : 256, 256, 0, stream>>>(gin, wzrh, zrp, Wo, wob);
  ln_zr_kernel<<<big ? 4096 : 2048, 256, 0, stream>>>(
      zrp, bz, br, gz, bez, gr, ber, hprev, x, zbuf, cand, Wo, wob);
  gemm64<<<dim3(32, 4), 256, 0, stream>>>(cand, wzrh + (size_t)1024 * 1024, hpre, B_, 512, K1_);
  ln_h_kernel<<<B_, 256, 0, stream>>>(hpre, bh, gh, beh, zbuf, hprev, out_h, htb);

  if (big) {
    gemm_out256<<<1576, 512, 0, stream>>>(htb, wob, bo, out_y);
  } else {
    gemm_out_kernel<<<dim3(16, 393), 256, 0, stream>>>(htb, Wo, bo, out_y);
  }
}

// Round 16
// 311.614 us; speedup vs baseline: 1.1811x; 1.1811x over previous
//
#include <hip/hip_runtime.h>
#include <hip/hip_bf16.h>
#include <cstdint>

typedef __bf16 bf16;
typedef bf16 bf16x4 __attribute__((ext_vector_type(4)));
typedef bf16 bf16x8 __attribute__((ext_vector_type(8)));
typedef float f32x4 __attribute__((ext_vector_type(4)));

#define B_  2048
#define E_  512
#define H_  512
#define V_  50257
#define K1_ 1024
#define VPAD_ 50432   // 197*256

// Wo conversion split (float4 units)
#define CONV_TOT  6432896   // V_*512/4
#define CONV_PAD  6455296   // VPAD_*512/4
#define CONV_HALF 3216448

#define BAR() __builtin_amdgcn_s_barrier()
#define WAIT_LGKM0() do { asm volatile("s_waitcnt lgkmcnt(0)" ::: "memory"); \
                          __builtin_amdgcn_sched_barrier(0); } while (0)

__device__ __forceinline__ void gload_lds16(const void* g, void* l) {
  __builtin_amdgcn_global_load_lds(
      (const __attribute__((address_space(1))) void*)g,
      (__attribute__((address_space(3))) void*)l, 16, 0, 0);
}

__device__ __forceinline__ float wave_sum(float v) {
#pragma unroll
  for (int o = 32; o > 0; o >>= 1) v += __shfl_xor(v, o, 64);
  return v;
}

__device__ __forceinline__ void cvt_store4(const float* __restrict__ src,
                                           bf16* __restrict__ dst, size_t e) {
  f32x4 v = *reinterpret_cast<const f32x4*>(src + e);
  bf16x4 t; t[0]=(bf16)v[0]; t[1]=(bf16)v[1]; t[2]=(bf16)v[2]; t[3]=(bf16)v[3];
  *reinterpret_cast<bf16x4*>(dst + e) = t;
}

// ---------------------------------------------------------------------------
// prep_small: gru_in bf16 [2048][1024]; wzrh bf16 [1536][1024]  (~7.5 MB)
// ---------------------------------------------------------------------------
__global__ __launch_bounds__(256) void prep_kernel(
    const float* __restrict__ hprev, const float* __restrict__ x,
    const float* __restrict__ Wz, const float* __restrict__ Wr,
    const float* __restrict__ Wh,
    bf16* __restrict__ gin, bf16* __restrict__ wzrh)
{
  const int i = blockIdx.x * 256 + threadIdx.x;
  constexpr int N1 = B_ * K1_ / 4;
  constexpr int N2 = 1536 * K1_ / 4;
  if (i < N1) {
    int e = i * 4;
    int m = e >> 10, k = e & 1023;
    const float* src = (k < 512) ? (hprev + (size_t)m * 512 + k)
                                 : (x + (size_t)m * 512 + (k - 512));
    f32x4 v = *reinterpret_cast<const f32x4*>(src);
    bf16x4 t; t[0]=(bf16)v[0]; t[1]=(bf16)v[1]; t[2]=(bf16)v[2]; t[3]=(bf16)v[3];
    *reinterpret_cast<bf16x4*>(gin + e) = t;
  } else if (i < N1 + N2) {
    int e = (i - N1) * 4;
    int which = e >> 19;
    int off = e & ((1 << 19) - 1);
    const float* W = (which == 0) ? Wz : (which == 1) ? Wr : Wh;
    f32x4 v = *reinterpret_cast<const f32x4*>(W + off);
    bf16x4 t; t[0]=(bf16)v[0]; t[1]=(bf16)v[1]; t[2]=(bf16)v[2]; t[3]=(bf16)v[3];
    *reinterpret_cast<bf16x4*>(wzrh + e) = t;
  }
}

// ---------------------------------------------------------------------------
// gemm64_zr: BM=64, BN=128, BK=64 GEMM for z/r pre-acts (M=2048,N=1024,K=1024)
// blocks [256, 2304) convert the FIRST half of Wo fp32 -> wob bf16.
// ---------------------------------------------------------------------------
__global__ __launch_bounds__(256) void gemm64_zr(
    const bf16* __restrict__ A, const bf16* __restrict__ Bm,
    float* __restrict__ C,
    const float* __restrict__ Wo, bf16* __restrict__ wob)
{
  const int bx = blockIdx.x;
  const int tid = threadIdx.x;
  if (bx >= 256) {               // Wo conversion, first half
    const size_t cb = bx - 256;
    for (size_t idx = cb * 256 + tid; idx < CONV_HALF; idx += (size_t)2048 * 256)
      cvt_store4(Wo, wob, idx * 4);
    return;
  }
  constexpr int N = 1024, K = K1_;
  __shared__ bf16 As[2][64 * 64];
  __shared__ bf16 Bs[2][128 * 64];
  const int wid = tid >> 6, lane = tid & 63;
  const int bm = bx & 31, bn = bx >> 5;
  const int wm = (wid >> 1) * 32, wn = (wid & 1) * 64;
  f32x4 acc[2][4] = {};
  const size_t a_row0 = (size_t)bm * 64;
  const size_t b_row0 = (size_t)bn * 128;

  auto STAGE = [&](int buf, int k0) {
#pragma unroll
    for (int i = 0; i < 2; ++i) {
      int base = i * 256 + wid * 64;
      int idx = base + lane;
      int row = idx >> 3;
      int col = ((idx & 7) ^ (row & 7)) << 3;
      gload_lds16(A + (a_row0 + row) * K + (k0 + col), &As[buf][base * 8]);
    }
#pragma unroll
    for (int i = 0; i < 4; ++i) {
      int base = i * 256 + wid * 64;
      int idx = base + lane;
      int row = idx >> 3;
      int col = ((idx & 7) ^ (row & 7)) << 3;
      gload_lds16(Bm + (b_row0 + row) * K + (k0 + col), &Bs[buf][base * 8]);
    }
  };

  auto COMPUTE = [&](int buf) {
#pragma unroll
    for (int kk = 0; kk < 2; ++kk) {
      bf16x8 af[2], bb[4];
#pragma unroll
      for (int i = 0; i < 2; ++i) {
        int ra = wm + i * 16 + (lane & 15);
        int ca = (kk * 32 + (lane >> 4) * 8) ^ ((ra & 7) << 3);
        af[i] = *reinterpret_cast<const bf16x8*>(&As[buf][ra * 64 + ca]);
      }
#pragma unroll
      for (int j = 0; j < 4; ++j) {
        int rb = wn + j * 16 + (lane & 15);
        int cb2 = (kk * 32 + (lane >> 4) * 8) ^ ((rb & 7) << 3);
        bb[j] = *reinterpret_cast<const bf16x8*>(&Bs[buf][rb * 64 + cb2]);
      }
      __builtin_amdgcn_s_setprio(1);
#pragma unroll
      for (int i = 0; i < 2; ++i)
#pragma unroll
        for (int j = 0; j < 4; ++j)
          acc[i][j] = __builtin_amdgcn_mfma_f32_16x16x32_bf16(af[i], bb[j], acc[i][j], 0, 0, 0);
      __builtin_amdgcn_s_setprio(0);
    }
  };

  STAGE(0, 0);
  asm volatile("s_waitcnt vmcnt(0)" ::: "memory");
  __syncthreads();
  const int nt = K >> 6;
  int cur = 0;
  for (int t = 0; t < nt - 1; ++t) {
    STAGE(cur ^ 1, (t + 1) << 6);
    COMPUTE(cur);
    asm volatile("s_waitcnt vmcnt(0)" ::: "memory");
    __syncthreads();
    cur ^= 1;
  }
  COMPUTE(cur);

  const int r0 = (lane >> 4) * 4, cc = lane & 15;
#pragma unroll
  for (int i = 0; i < 2; ++i)
#pragma unroll
    for (int j = 0; j < 4; ++j) {
      int n = bn * 128 + wn + j * 16 + cc;
#pragma unroll
      for (int q = 0; q < 4; ++q) {
        int mm = bm * 64 + wm + i * 16 + r0 + q;
        C[(size_t)mm * N + n] = acc[i][j][q];
      }
    }
}

// ---------------------------------------------------------------------------
// gemm64 (generic, for h pre-act): BM=64, BN=128, BK=64
// ---------------------------------------------------------------------------
__global__ __launch_bounds__(256) void gemm64(
    const bf16* __restrict__ A, const bf16* __restrict__ Bm,
    float* __restrict__ C, int M, int N, int K)
{
  __shared__ bf16 As[2][64 * 64];
  __shared__ bf16 Bs[2][128 * 64];
  const int tid = threadIdx.x;
  const int wid = tid >> 6, lane = tid & 63;
  const int bm = blockIdx.x, bn = blockIdx.y;
  const int wm = (wid >> 1) * 32, wn = (wid & 1) * 64;
  f32x4 acc[2][4] = {};
  const size_t a_row0 = (size_t)bm * 64;
  const size_t b_row0 = (size_t)bn * 128;

  auto STAGE = [&](int buf, int k0) {
#pragma unroll
    for (int i = 0; i < 2; ++i) {
      int base = i * 256 + wid * 64;
      int idx = base + lane;
      int row = idx >> 3;
      int col = ((idx & 7) ^ (row & 7)) << 3;
      gload_lds16(A + (a_row0 + row) * K + (k0 + col), &As[buf][base * 8]);
    }
#pragma unroll
    for (int i = 0; i < 4; ++i) {
      int base = i * 256 + wid * 64;
      int idx = base + lane;
      int row = idx >> 3;
      int col = ((idx & 7) ^ (row & 7)) << 3;
      gload_lds16(Bm + (b_row0 + row) * K + (k0 + col), &Bs[buf][base * 8]);
    }
  };

  auto COMPUTE = [&](int buf) {
#pragma unroll
    for (int kk = 0; kk < 2; ++kk) {
      bf16x8 af[2], bb[4];
#pragma unroll
      for (int i = 0; i < 2; ++i) {
        int ra = wm + i * 16 + (lane & 15);
        int ca = (kk * 32 + (lane >> 4) * 8) ^ ((ra & 7) << 3);
        af[i] = *reinterpret_cast<const bf16x8*>(&As[buf][ra * 64 + ca]);
      }
#pragma unroll
      for (int j = 0; j < 4; ++j) {
        int rb = wn + j * 16 + (lane & 15);
        int cb = (kk * 32 + (lane >> 4) * 8) ^ ((rb & 7) << 3);
        bb[j] = *reinterpret_cast<const bf16x8*>(&Bs[buf][rb * 64 + cb]);
      }
      __builtin_amdgcn_s_setprio(1);
#pragma unroll
      for (int i = 0; i < 2; ++i)
#pragma unroll
        for (int j = 0; j < 4; ++j)
          acc[i][j] = __builtin_amdgcn_mfma_f32_16x16x32_bf16(af[i], bb[j], acc[i][j], 0, 0, 0);
      __builtin_amdgcn_s_setprio(0);
    }
  };

  STAGE(0, 0);
  asm volatile("s_waitcnt vmcnt(0)" ::: "memory");
  __syncthreads();
  const int nt = K >> 6;
  int cur = 0;
  for (int t = 0; t < nt - 1; ++t) {
    STAGE(cur ^ 1, (t + 1) << 6);
    COMPUTE(cur);
    asm volatile("s_waitcnt vmcnt(0)" ::: "memory");
    __syncthreads();
    cur ^= 1;
  }
  COMPUTE(cur);

  const int r0 = (lane >> 4) * 4, cc = lane & 15;
#pragma unroll
  for (int i = 0; i < 2; ++i)
#pragma unroll
    for (int j = 0; j < 4; ++j) {
      int n = bn * 128 + wn + j * 16 + cc;
#pragma unroll
      for (int q = 0; q < 4; ++q) {
        int mm = bm * 64 + wm + i * 16 + r0 + q;
        C[(size_t)mm * N + n] = acc[i][j][q];
      }
    }
}

// ---------------------------------------------------------------------------
// LN(+bias) + sigmoid for z and r; blocks [2048,4096) convert Wo 2nd half+pad
// ---------------------------------------------------------------------------
__global__ __launch_bounds__(256) void ln_zr_kernel(
    const float* __restrict__ zrp,
    const float* __restrict__ bz, const float* __restrict__ br,
    const float* __restrict__ gz, const float* __restrict__ bez,
    const float* __restrict__ gr, const float* __restrict__ ber,
    const float* __restrict__ hprev, const float* __restrict__ x,
    float* __restrict__ zbuf, bf16* __restrict__ cand,
    const float* __restrict__ Wo, bf16* __restrict__ wob)
{
  const int bx = blockIdx.x, tid = threadIdx.x;
  if (bx >= 2048) {
    const size_t cb = bx - 2048;
    for (size_t idx = CONV_HALF + cb * 256 + tid; idx < CONV_PAD;
         idx += (size_t)2048 * 256) {
      if (idx < CONV_TOT) {
        cvt_store4(Wo, wob, idx * 4);
      } else {
        bf16x4 t = {};
        *reinterpret_cast<bf16x4*>(wob + idx * 4) = t;
      }
    }
    return;
  }
  const int m = bx;
  const int wid = tid >> 6, lane = tid & 63;
  float zv[2], rv[2];
  float s0 = 0, s1 = 0, s2 = 0, s3 = 0;
#pragma unroll
  for (int e = 0; e < 2; ++e) {
    int n = tid + e * 256;
    float a = zrp[(size_t)m * 1024 + n] + bz[n];
    float b = zrp[(size_t)m * 1024 + 512 + n] + br[n];
    zv[e] = a; rv[e] = b;
    s0 += a; s1 += a * a; s2 += b; s3 += b * b;
  }
  s0 = wave_sum(s0); s1 = wave_sum(s1); s2 = wave_sum(s2); s3 = wave_sum(s3);
  __shared__ float red[4][4];
  if (lane == 0) { red[wid][0] = s0; red[wid][1] = s1; red[wid][2] = s2; red[wid][3] = s3; }
  __syncthreads();
  float zs = red[0][0] + red[1][0] + red[2][0] + red[3][0];
  float zq = red[0][1] + red[1][1] + red[2][1] + red[3][1];
  float rs = red[0][2] + red[1][2] + red[2][2] + red[3][2];
  float rq = red[0][3] + red[1][3] + red[2][3] + red[3][3];
  float zm = zs * (1.f / 512.f), zvr = zq * (1.f / 512.f) - zm * zm;
  float rm = rs * (1.f / 512.f), rvr = rq * (1.f / 512.f) - rm * rm;
  float zrs_ = rsqrtf(zvr + 1e-5f), rrs = rsqrtf(rvr + 1e-5f);
#pragma unroll
  for (int e = 0; e < 2; ++e) {
    int n = tid + e * 256;
    float zval = 1.f / (1.f + expf(-((zv[e] - zm) * zrs_ * gz[n] + bez[n])));
    float rval = 1.f / (1.f + expf(-((rv[e] - rm) * rrs * gr[n] + ber[n])));
    zbuf[(size_t)m * 512 + n] = zval;
    cand[(size_t)m * 1024 + n] = (bf16)(hprev[(size_t)m * 512 + n] * rval);
    cand[(size_t)m * 1024 + 512 + n] = (bf16)(x[(size_t)m * 512 + n]);
  }
}

// ---------------------------------------------------------------------------
// LN(+bias) + tanh for h_new; h_t = (1-z)*h_prev + z*h_new
// ---------------------------------------------------------------------------
__global__ __launch_bounds__(256) void ln_h_kernel(
    const float* __restrict__ hpre, const float* __restrict__ bh,
    const float* __restrict__ gh, const float* __restrict__ beh,
    const float* __restrict__ zbuf, const float* __restrict__ hprev,
    float* __restrict__ outh, bf16* __restrict__ htb)
{
  const int m = blockIdx.x, tid = threadIdx.x;
  const int wid = tid >> 6, lane = tid & 63;
  float v[2];
  float s0 = 0, s1 = 0;
#pragma unroll
  for (int e = 0; e < 2; ++e) {
    int n = tid + e * 256;
    float a = hpre[(size_t)m * 512 + n] + bh[n];
    v[e] = a; s0 += a; s1 += a * a;
  }
  s0 = wave_sum(s0); s1 = wave_sum(s1);
  __shared__ float red[4][2];
  if (lane == 0) { red[wid][0] = s0; red[wid][1] = s1; }
  __syncthreads();
  float ss = red[0][0] + red[1][0] + red[2][0] + red[3][0];
  float sq = red[0][1] + red[1][1] + red[2][1] + red[3][1];
  float mean = ss * (1.f / 512.f), var = sq * (1.f / 512.f) - mean * mean;
  float rstd = rsqrtf(var + 1e-5f);
#pragma unroll
  for (int e = 0; e < 2; ++e) {
    int n = tid + e * 256;
    float hn = tanhf((v[e] - mean) * rstd * gh[n] + beh[n]);
    float z = zbuf[(size_t)m * 512 + n];
    float ht = (1.f - z) * hprev[(size_t)m * 512 + n] + z * hn;
    outh[(size_t)m * 512 + n] = ht;
    htb[(size_t)m * 512 + n] = (bf16)ht;
  }
}

// ---------------------------------------------------------------------------
// big GEMM v9 (r13-exact): 8-phase template, 256x256, BK=64, 8 waves 2Mx4N,
// LDS [parity][op][half][128x64] = 128 KB, #pragma unroll 1, runtime `pre`.
// Epilogue after loop, j innermost (L2 write-combine friendly).
// ---------------------------------------------------------------------------
__global__ __launch_bounds__(512, 2) void gemm_out256(
    const bf16* __restrict__ A, const bf16* __restrict__ Wb,
    const float* __restrict__ bo, float* __restrict__ Y)
{
  __shared__ bf16 lds[2][2][2][128 * 64];
  const int tid = threadIdx.x;
  const int lane = tid & 63;
  const int wid = tid >> 6;
  const int wr = wid >> 2, wc = wid & 3;
  const int hw = blockIdx.x;
  const int logical = (hw & 7) * 197 + (hw >> 3);
  const int bm = logical & 7;
  const int bn = logical >> 3;
  const size_t a_row0 = (size_t)bm * 256;
  const size_t b_row0 = (size_t)bn * 256;
  f32x4 acc[8][4] = {};

  auto STAGE = [&](int p, int op, int h, int ks) {
    const bf16* src = op ? Wb : A;
    const size_t r0 = (op ? b_row0 : a_row0) + h * 128;
    const int k0 = ks << 6;
#pragma unroll
    for (int l = 0; l < 2; ++l) {
      int idx = l * 512 + tid;
      int row = idx >> 3;
      int ch = ((idx & 7) ^ (row & 7)) << 3;
      gload_lds16(src + (r0 + row) * 512 + k0 + ch,
                  &lds[p][op][h][(l * 512 + (tid & ~63)) * 8]);
    }
  };

  auto rdA = [&](int p, int i, int kk) -> bf16x8 {
    int lr = i * 16 + (lane & 15);
    int ch = ((kk * 4 + (lane >> 4)) ^ (lr & 7)) << 3;
    return *reinterpret_cast<const bf16x8*>(&lds[p][0][wr][lr * 64 + ch]);
  };
  auto rdB = [&](int p, int j, int kk) -> bf16x8 {
    int gr = wc * 64 + j * 16 + (lane & 15);
    int lr = gr & 127;
    int ch = ((kk * 4 + (lane >> 4)) ^ (lr & 7)) << 3;
    return *reinterpret_cast<const bf16x8*>(&lds[p][1][wc >> 1][lr * 64 + ch]);
  };

  bf16x8 a0[4][2], a1[4][2], bb0[2][2], bb1[2][2];

  auto MM = [&](bf16x8 (&af)[4][2], bf16x8 (&bf)[2][2], int ib, int jb) {
    __builtin_amdgcn_s_setprio(1);
#pragma unroll
    for (int i = 0; i < 4; ++i)
#pragma unroll
      for (int j = 0; j < 2; ++j)
#pragma unroll
        for (int kk = 0; kk < 2; ++kk)
          acc[ib + i][jb + j] =
              __builtin_amdgcn_mfma_f32_16x16x32_bf16(af[i][kk], bf[j][kk],
                                                      acc[ib + i][jb + j], 0, 0, 0);
    __builtin_amdgcn_s_setprio(0);
  };

  STAGE(0, 0, 0, 0); STAGE(0, 0, 1, 0); STAGE(0, 1, 0, 0); STAGE(0, 1, 1, 0);
  STAGE(1, 0, 0, 1); STAGE(1, 0, 1, 1);
  asm volatile("s_waitcnt vmcnt(4)" ::: "memory");
  BAR();

#pragma unroll 1
  for (int it = 0; it < 4; ++it) {
    const int s = 2 * it;
    const bool pre = (it < 3);
    // ph1
#pragma unroll
    for (int i = 0; i < 4; ++i) { a0[i][0] = rdA(0, i, 0); a0[i][1] = rdA(0, i, 1); }
#pragma unroll
    for (int j = 0; j < 2; ++j) { bb0[j][0] = rdB(0, j, 0); bb0[j][1] = rdB(0, j, 1); }
    STAGE(1, 1, 0, s + 1);
    BAR(); WAIT_LGKM0();
    MM(a0, bb0, 0, 0);
    BAR();
    // ph2
#pragma unroll
    for (int i = 0; i < 4; ++i) { a1[i][0] = rdA(0, 4 + i, 0); a1[i][1] = rdA(0, 4 + i, 1); }
    STAGE(1, 1, 1, s + 1);
    BAR(); WAIT_LGKM0();
    MM(a1, bb0, 4, 0);
    BAR();
    // ph3
#pragma unroll
    for (int j = 0; j < 2; ++j) { bb1[j][0] = rdB(0, 2 + j, 0); bb1[j][1] = rdB(0, 2 + j, 1); }
    if (pre) STAGE(0, 0, 0, s + 2);
    BAR(); WAIT_LGKM0();
    MM(a0, bb1, 0, 2);
    BAR();
    // ph4
    if (pre) { STAGE(0, 1, 0, s + 2);
               asm volatile("s_waitcnt vmcnt(4)" ::: "memory"); }
    else     { asm volatile("s_waitcnt vmcnt(0)" ::: "memory"); }
    BAR();
    MM(a1, bb1, 4, 2);
    BAR();
    // ph5
#pragma unroll
    for (int i = 0; i < 4; ++i) { a0[i][0] = rdA(1, i, 0); a0[i][1] = rdA(1, i, 1); }
#pragma unroll
    for (int j = 0; j < 2; ++j) { bb0[j][0] = rdB(1, j, 0); bb0[j][1] = rdB(1, j, 1); }
    if (pre) STAGE(0, 0, 1, s + 2);
    BAR(); WAIT_LGKM0();
    MM(a0, bb0, 0, 0);
    BAR();
    // ph6
#pragma unroll
    for (int i = 0; i < 4; ++i) { a1[i][0] = rdA(1, 4 + i, 0); a1[i][1] = rdA(1, 4 + i, 1); }
    if (pre) STAGE(0, 1, 1, s + 2);
    BAR(); WAIT_LGKM0();
    MM(a1, bb0, 4, 0);
    BAR();
    // ph7
#pragma unroll
    for (int j = 0; j < 2; ++j) { bb1[j][0] = rdB(1, 2 + j, 0); bb1[j][1] = rdB(1, 2 + j, 1); }
    if (pre) STAGE(1, 0, 0, s + 3);
    BAR(); WAIT_LGKM0();
    MM(a0, bb1, 0, 2);
    BAR();
    // ph8
    if (pre) { STAGE(1, 0, 1, s + 3);
               asm volatile("s_waitcnt vmcnt(4)" ::: "memory"); }
    BAR();
    MM(a1, bb1, 4, 2);
    BAR();
  }

  // epilogue: row-contiguous cached stores (j innermost)
  const int r0q = (lane >> 4) * 4, cc = lane & 15;
  const int rowbase = (int)a_row0 + wr * 128;
  const int colbase = (int)b_row0 + wc * 64;
  float bia[4]; bool val[4];
#pragma unroll
  for (int j = 0; j < 4; ++j) {
    int n = colbase + j * 16 + cc;
    val[j] = (n < V_);
    bia[j] = val[j] ? bo[n] : 0.f;
  }
#pragma unroll
  for (int i = 0; i < 8; ++i) {
#pragma unroll
    for (int q = 0; q < 4; ++q) {
      size_t rowoff = (size_t)(rowbase + i * 16 + r0q + q) * V_;
#pragma unroll
      for (int j = 0; j < 4; ++j) {
        if (val[j]) Y[rowoff + colbase + j * 16 + cc] = acc[i][j][q] + bia[j];
      }
    }
  }
}

// ---------------------------------------------------------------------------
// fallback path (ws too small): fp32 Wo reg-staged GEMM
// ---------------------------------------------------------------------------
__global__ __launch_bounds__(256) void gemm_out_kernel(
    const bf16* __restrict__ A, const float* __restrict__ Wo,
    const float* __restrict__ bo, float* __restrict__ Y)
{
  __shared__ bf16 As[128 * 64];
  __shared__ bf16 Bs[128 * 64];
  constexpr int K = 512;
  const int tid = threadIdx.x;
  const int wid = tid >> 6, lane = tid & 63;
  const int bm = blockIdx.x, bn = blockIdx.y;
  const int wm = (wid >> 1) * 64, wn = (wid & 1) * 64;
  f32x4 acc[4][4] = {};

  for (int k0 = 0; k0 < K; k0 += 64) {
#pragma unroll
    for (int i = 0; i < 4; ++i) {
      int base = i * 256 + wid * 64;
      int idx = base + lane;
      int row = idx >> 3, col = (idx & 7) << 3;
      gload_lds16(A + ((size_t)bm * 128 + row) * K + (k0 + col), &As[base * 8]);
    }
#pragma unroll
    for (int i = 0; i < 8; ++i) {
      int idx = i * 256 + tid;
      int row = idx >> 4;
      int c4 = (idx & 15) * 4;
      int n = bn * 128 + row;
      int nc = (n < V_) ? n : (V_ - 1);
      f32x4 v = *reinterpret_cast<const f32x4*>(Wo + (size_t)nc * K + k0 + c4);
      bf16x4 t; t[0]=(bf16)v[0]; t[1]=(bf16)v[1]; t[2]=(bf16)v[2]; t[3]=(bf16)v[3];
      *reinterpret_cast<bf16x4*>(&Bs[row * 64 + c4]) = t;
    }
    asm volatile("s_waitcnt vmcnt(0)" ::: "memory");
    __syncthreads();
#pragma unroll
    for (int kk = 0; kk < 2; ++kk) {
      bf16x8 af[4], bb[4];
#pragma unroll
      for (int i = 0; i < 4; ++i)
        af[i] = *reinterpret_cast<const bf16x8*>(
            &As[(wm + i * 16 + (lane & 15)) * 64 + kk * 32 + (lane >> 4) * 8]);
#pragma unroll
      for (int j = 0; j < 4; ++j)
        bb[j] = *reinterpret_cast<const bf16x8*>(
            &Bs[(wn + j * 16 + (lane & 15)) * 64 + kk * 32 + (lane >> 4) * 8]);
#pragma unroll
      for (int i = 0; i < 4; ++i)
#pragma unroll
        for (int j = 0; j < 4; ++j)
          acc[i][j] = __builtin_amdgcn_mfma_f32_16x16x32_bf16(af[i], bb[j], acc[i][j], 0, 0, 0);
    }
    __syncthreads();
  }

  const int r0 = (lane >> 4) * 4, cc = lane & 15;
#pragma unroll
  for (int i = 0; i < 4; ++i)
#pragma unroll
    for (int j = 0; j < 4; ++j) {
      int n = bn * 128 + wn + j * 16 + cc;
      if (n < V_) {
        float bia = bo[n];
#pragma unroll
        for (int q = 0; q < 4; ++q) {
          int mm = bm * 128 + wm + i * 16 + r0 + q;
          Y[(size_t)mm * V_ + n] = acc[i][j][q] + bia;
        }
      }
    }
}

// ---------------------------------------------------------------------------
extern "C" void kernel_launch(void* const* d_in, const int* in_sizes, int n_in,
                              void* d_out, int out_size, void* d_ws, size_t ws_size,
                              hipStream_t stream) {
  const float* x     = (const float*)d_in[0];
  const float* hprev = (const float*)d_in[1];
  const float* Wz    = (const float*)d_in[2];
  const float* bz    = (const float*)d_in[3];
  const float* gz    = (const float*)d_in[4];
  const float* bez   = (const float*)d_in[5];
  const float* Wr    = (const float*)d_in[6];
  const float* br    = (const float*)d_in[7];
  const float* gr    = (const float*)d_in[8];
  const float* ber   = (const float*)d_in[9];
  const float* Wh    = (const float*)d_in[10];
  const float* bh    = (const float*)d_in[11];
  const float* gh    = (const float*)d_in[12];
  const float* beh   = (const float*)d_in[13];
  const float* Wo    = (const float*)d_in[14];
  const float* bo    = (const float*)d_in[15];

  float* out_h = (float*)d_out;
  float* out_y = out_h + (size_t)B_ * H_;

  char* ws = (char*)d_ws;
  bf16*  gin  = (bf16*)(ws);                      // 4 MB   [2048][1024]
  bf16*  wzrh = (bf16*)(ws + ((size_t)4 << 20));  // 3 MB   [1536][1024]
  float* zrp  = (float*)(ws + ((size_t)7 << 20)); // 8 MB   [2048][1024]
  float* zbuf = (float*)(ws + ((size_t)15 << 20));// 4 MB   [2048][512]
  bf16*  cand = (bf16*)(ws + ((size_t)19 << 20)); // 4 MB   [2048][1024]
  float* hpre = (float*)(ws + ((size_t)23 << 20));// 4 MB   [2048][512]
  bf16*  htb  = (bf16*)(ws + ((size_t)27 << 20)); // 2 MB   [2048][512]
  bf16*  wob  = (bf16*)(ws + ((size_t)29 << 20)); // 51.6 MB [VPAD_][512]

  constexpr size_t NEED = ((size_t)29 << 20) + (size_t)VPAD_ * 512 * 2;
  const bool big = (ws_size >= NEED);

  prep_kernel<<<3584, 256, 0, stream>>>(hprev, x, Wz, Wr, Wh, gin, wzrh);
  gemm64_zr<<<big ? 2304 : 256, 256, 0, stream>>>(gin, wzrh, zrp, Wo, wob);
  ln_zr_kernel<<<big ? 4096 : 2048, 256, 0, stream>>>(
      zrp, bz, br, gz, bez, gr, ber, hprev, x, zbuf, cand, Wo, wob);
  gemm64<<<dim3(32, 4), 256, 0, stream>>>(cand, wzrh + (size_t)1024 * 1024, hpre, B_, 512, K1_);
  ln_h_kernel<<<B_, 256, 0, stream>>>(hpre, bh, gh, beh, zbuf, hprev, out_h, htb);

  if (big) {
    gemm_out256<<<1576, 512, 0, stream>>>(htb, wob, bo, out_y);
  } else {
    gemm_out_kernel<<<dim3(16, 393), 256, 0, stream>>>(htb, Wo, bo, out_y);
  }
}